// Round 1
// baseline (687.370 us; speedup 1.0000x reference)
//
#include <hip/hip_runtime.h>

// Problem constants (fixed by the reference): query (32,1,1024) f32, keys (32,4096,1024) f32
#define BATCH 32
#define S 4096
#define H 1024
#define H4 (H / 4)            // 256 float4 per row
#define NCHUNK 16             // S-chunks per batch -> grid = 16*32 = 512 blocks (2/CU)
#define KPC (S / NCHUNK)      // 256 keys per chunk
#define BLOCK 256
#define NWAVE (BLOCK / 64)    // 4 waves
#define KPW (KPC / NWAVE)     // 64 keys per wave

// Pass 1: fused scores + online-softmax partial context. One read of keys total.
// Each wave streams 64 key rows; lane i holds float4 columns {i, i+64, i+128, i+192}.
__global__ __launch_bounds__(BLOCK) void attn_pass1(
    const float* __restrict__ query, const float* __restrict__ keys,
    float* __restrict__ scores,         // raw scores -> d_out weights region (normalized by pass 2)
    float* __restrict__ po,             // [BATCH][NCHUNK][H] partial context (unnormalized)
    float* __restrict__ pm,             // [BATCH][NCHUNK] partial max
    float* __restrict__ pl)             // [BATCH][NCHUNK] partial sum
{
  const int chunk = blockIdx.x;
  const int b     = blockIdx.y;
  const int lane  = threadIdx.x & 63;
  const int wave  = threadIdx.x >> 6;

  // Query fragment: 16 floats/lane, same layout as key fragments.
  const float4* q4 = (const float4*)(query + (size_t)b * H);
  const float4 q0 = q4[lane], q1 = q4[lane + 64], q2 = q4[lane + 128], q3 = q4[lane + 192];

  const int s0 = chunk * KPC + wave * KPW;
  const float4* kp = (const float4*)(keys + ((size_t)b * S + s0) * (size_t)H);

  // Preload first key row (prefetch pipeline).
  float4 k0 = kp[lane], k1 = kp[lane + 64], k2 = kp[lane + 128], k3 = kp[lane + 192];

  float m = -3.0e38f, l = 0.0f;
  float4 o0 = {0,0,0,0}, o1 = {0,0,0,0}, o2 = {0,0,0,0}, o3 = {0,0,0,0};

  for (int i = 0; i < KPW; ++i) {
    const float4* kn = kp + H4;
    float4 n0, n1, n2, n3;
    if (i + 1 < KPW) {  // prefetch next row while we reduce the current one
      n0 = kn[lane]; n1 = kn[lane + 64]; n2 = kn[lane + 128]; n3 = kn[lane + 192];
    }
    float d = k0.x*q0.x + k0.y*q0.y + k0.z*q0.z + k0.w*q0.w
            + k1.x*q1.x + k1.y*q1.y + k1.z*q1.z + k1.w*q1.w
            + k2.x*q2.x + k2.y*q2.y + k2.z*q2.z + k2.w*q2.w
            + k3.x*q3.x + k3.y*q3.y + k3.z*q3.z + k3.w*q3.w;
    #pragma unroll
    for (int off = 1; off < 64; off <<= 1) d += __shfl_xor(d, off);  // all lanes get full dot

    if (lane == 0) scores[(size_t)b * S + (s0 + i)] = d;

    // Online softmax update; key row is already in registers -> P*V costs no memory.
    const float mn = fmaxf(m, d);
    const float sc = __expf(m - mn);   // 0 on first iter (m = -3e38)
    const float p  = __expf(d - mn);
    l = l * sc + p;
    o0.x = o0.x*sc + p*k0.x; o0.y = o0.y*sc + p*k0.y; o0.z = o0.z*sc + p*k0.z; o0.w = o0.w*sc + p*k0.w;
    o1.x = o1.x*sc + p*k1.x; o1.y = o1.y*sc + p*k1.y; o1.z = o1.z*sc + p*k1.z; o1.w = o1.w*sc + p*k1.w;
    o2.x = o2.x*sc + p*k2.x; o2.y = o2.y*sc + p*k2.y; o2.z = o2.z*sc + p*k2.z; o2.w = o2.w*sc + p*k2.w;
    o3.x = o3.x*sc + p*k3.x; o3.y = o3.y*sc + p*k3.y; o3.z = o3.z*sc + p*k3.z; o3.w = o3.w*sc + p*k3.w;
    m = mn;
    k0 = n0; k1 = n1; k2 = n2; k3 = n3;
    kp = kn;
  }

  // Combine the 4 waves' (m, l, o) within the block via LDS.
  __shared__ float lds_o[NWAVE][H];     // 16 KiB
  __shared__ float lds_m[NWAVE], lds_l[NWAVE];
  float4* lo = (float4*)lds_o[wave];
  lo[lane] = o0; lo[lane + 64] = o1; lo[lane + 128] = o2; lo[lane + 192] = o3;
  if (lane == 0) { lds_m[wave] = m; lds_l[wave] = l; }
  __syncthreads();

  const int t = threadIdx.x;
  const float bm = fmaxf(fmaxf(lds_m[0], lds_m[1]), fmaxf(lds_m[2], lds_m[3]));
  float bl = 0.0f;
  float4 acc = {0,0,0,0};
  #pragma unroll
  for (int w = 0; w < NWAVE; ++w) {
    const float scw = __expf(lds_m[w] - bm);
    bl += lds_l[w] * scw;
    const float4 ow = ((const float4*)lds_o[w])[t];
    acc.x += ow.x*scw; acc.y += ow.y*scw; acc.z += ow.z*scw; acc.w += ow.w*scw;
  }
  ((float4*)po)[((size_t)b * NCHUNK + chunk) * H4 + t] = acc;
  if (t == 0) { pm[b * NCHUNK + chunk] = bm; pl[b * NCHUNK + chunk] = bl; }
}

// Pass 2: merge the 16 chunk partials per batch, emit context and normalized weights.
__global__ __launch_bounds__(256) void attn_pass2(
    const float* __restrict__ po, const float* __restrict__ pm, const float* __restrict__ pl,
    float* __restrict__ ctx, float* __restrict__ wts)
{
  const int b = blockIdx.x;
  const int t = threadIdx.x;
  __shared__ float s_scale[NCHUNK];
  __shared__ float s_m, s_invl;
  if (t == 0) {
    float m = -3.0e38f;
    for (int j = 0; j < NCHUNK; ++j) m = fmaxf(m, pm[b * NCHUNK + j]);
    float l = 0.0f;
    for (int j = 0; j < NCHUNK; ++j) {
      const float sc = __expf(pm[b * NCHUNK + j] - m);
      s_scale[j] = sc;
      l += pl[b * NCHUNK + j] * sc;
    }
    s_m = m; s_invl = 1.0f / l;
  }
  __syncthreads();
  const float m = s_m, invl = s_invl;

  float4 acc = {0,0,0,0};
  for (int j = 0; j < NCHUNK; ++j) {
    const float4 ow = ((const float4*)po)[((size_t)b * NCHUNK + j) * H4 + t];
    const float sc = s_scale[j];
    acc.x += ow.x*sc; acc.y += ow.y*sc; acc.z += ow.z*sc; acc.w += ow.w*sc;
  }
  acc.x *= invl; acc.y *= invl; acc.z *= invl; acc.w *= invl;
  ((float4*)ctx)[(size_t)b * H4 + t] = acc;

  // Normalize stored raw scores in place.
  for (int s = t; s < S; s += 256) {
    const float sc = wts[(size_t)b * S + s];
    wts[(size_t)b * S + s] = __expf(sc - m) * invl;
  }
}

extern "C" void kernel_launch(void* const* d_in, const int* in_sizes, int n_in,
                              void* d_out, int out_size, void* d_ws, size_t ws_size,
                              hipStream_t stream) {
  const float* query = (const float*)d_in[0];   // 32*1*1024
  const float* keys  = (const float*)d_in[1];   // 32*4096*1024

  float* ctx = (float*)d_out;                   // context: first 32*1024 floats
  float* wts = (float*)d_out + BATCH * H;       // weights: next 32*4096 floats

  float* po = (float*)d_ws;                     // 32*16*1024 floats = 2 MiB
  float* pm = po + (size_t)BATCH * NCHUNK * H;  // 512 floats
  float* pl = pm + BATCH * NCHUNK;              // 512 floats

  attn_pass1<<<dim3(NCHUNK, BATCH), BLOCK, 0, stream>>>(query, keys, wts, po, pm, pl);
  attn_pass2<<<BATCH, 256, 0, stream>>>(po, pm, pl, ctx, wts);
}

// Round 3
// 661.646 us; speedup vs baseline: 1.0389x; 1.0389x over previous
//
#include <hip/hip_runtime.h>

// Problem constants (fixed by the reference): query (32,1,1024) f32, keys (32,4096,1024) f32
#define BATCH 32
#define S 4096
#define H 1024
#define H4 (H / 4)            // 256 float4 per row
#define NCHUNK 32             // S-chunks per batch -> grid = 32*32 = 1024 blocks (4/CU, 4 waves/SIMD)
#define KPC (S / NCHUNK)      // 128 keys per chunk
#define BLOCK 256
#define NWAVE (BLOCK / 64)    // 4 waves
#define KPW (KPC / NWAVE)     // 32 keys per wave

// Native vector type: __builtin_nontemporal_load rejects HIP_vector_type (struct),
// but accepts clang ext_vector_type. Layout-identical to float4.
typedef float vfloat4 __attribute__((ext_vector_type(4)));

static __device__ __forceinline__ vfloat4 nt_load(const vfloat4* p) {
  return __builtin_nontemporal_load(p);
}

// Pass 1: fused scores + online-softmax partial context. One read of keys total.
// Each wave streams KPW key rows; lane i holds float4 columns {i, i+64, i+128, i+192}.
__global__ __launch_bounds__(BLOCK) void attn_pass1(
    const float* __restrict__ query, const float* __restrict__ keys,
    float* __restrict__ scores,         // raw scores -> d_out weights region (normalized by pass 2)
    float* __restrict__ po,             // [BATCH][NCHUNK][H] partial context (unnormalized)
    float* __restrict__ pm,             // [BATCH][NCHUNK] partial max
    float* __restrict__ pl)             // [BATCH][NCHUNK] partial sum
{
  const int chunk = blockIdx.x;
  const int b     = blockIdx.y;
  const int lane  = threadIdx.x & 63;
  const int wave  = threadIdx.x >> 6;

  // Query fragment: 16 floats/lane, same layout as key fragments (reused -> normal load).
  const vfloat4* q4 = (const vfloat4*)(query + (size_t)b * H);
  const vfloat4 q0 = q4[lane], q1 = q4[lane + 64], q2 = q4[lane + 128], q3 = q4[lane + 192];

  const int s0 = chunk * KPC + wave * KPW;
  const vfloat4* kp = (const vfloat4*)(keys + ((size_t)b * S + s0) * (size_t)H);

  // Preload first key row (1-deep prefetch pipeline; streaming -> nontemporal).
  vfloat4 k0 = nt_load(kp + lane), k1 = nt_load(kp + lane + 64),
          k2 = nt_load(kp + lane + 128), k3 = nt_load(kp + lane + 192);

  float m = -3.0e38f, l = 0.0f;
  vfloat4 o0 = {0,0,0,0}, o1 = {0,0,0,0}, o2 = {0,0,0,0}, o3 = {0,0,0,0};

  for (int i = 0; i < KPW; ++i) {
    // Unconditional prefetch with clamped pointer: last iteration re-reads the
    // current row (L2-hit) instead of branching — keeps loads hoisted and
    // exec-mask-free so vmcnt can retire behind the compute chain.
    const vfloat4* kn = (i + 1 < KPW) ? (kp + H4) : kp;
    const vfloat4 n0 = nt_load(kn + lane),       n1 = nt_load(kn + lane + 64),
                  n2 = nt_load(kn + lane + 128), n3 = nt_load(kn + lane + 192);

    float d = k0.x*q0.x + k0.y*q0.y + k0.z*q0.z + k0.w*q0.w
            + k1.x*q1.x + k1.y*q1.y + k1.z*q1.z + k1.w*q1.w
            + k2.x*q2.x + k2.y*q2.y + k2.z*q2.z + k2.w*q2.w
            + k3.x*q3.x + k3.y*q3.y + k3.z*q3.z + k3.w*q3.w;
    #pragma unroll
    for (int off = 1; off < 64; off <<= 1) d += __shfl_xor(d, off);  // all lanes get full dot

    if (lane == 0) scores[(size_t)b * S + (s0 + i)] = d;

    // Online softmax update; key row is already in registers -> P*V costs no memory.
    const float mn = fmaxf(m, d);
    const float sc = __expf(m - mn);   // 0 on first iter (m = -3e38)
    const float p  = __expf(d - mn);
    l = l * sc + p;
    o0 = o0*sc + p*k0;
    o1 = o1*sc + p*k1;
    o2 = o2*sc + p*k2;
    o3 = o3*sc + p*k3;
    m = mn;
    k0 = n0; k1 = n1; k2 = n2; k3 = n3;
    kp = kn;
  }

  // Combine the 4 waves' (m, l, o) within the block via LDS.
  __shared__ float lds_o[NWAVE][H];     // 16 KiB
  __shared__ float lds_m[NWAVE], lds_l[NWAVE];
  vfloat4* lo = (vfloat4*)lds_o[wave];
  lo[lane] = o0; lo[lane + 64] = o1; lo[lane + 128] = o2; lo[lane + 192] = o3;
  if (lane == 0) { lds_m[wave] = m; lds_l[wave] = l; }
  __syncthreads();

  const int t = threadIdx.x;
  const float bm = fmaxf(fmaxf(lds_m[0], lds_m[1]), fmaxf(lds_m[2], lds_m[3]));
  float bl = 0.0f;
  vfloat4 acc = {0,0,0,0};
  #pragma unroll
  for (int w = 0; w < NWAVE; ++w) {
    const float scw = __expf(lds_m[w] - bm);
    bl += lds_l[w] * scw;
    const vfloat4 ow = ((const vfloat4*)lds_o[w])[t];
    acc += ow * scw;
  }
  ((vfloat4*)po)[((size_t)b * NCHUNK + chunk) * H4 + t] = acc;
  if (t == 0) { pm[b * NCHUNK + chunk] = bm; pl[b * NCHUNK + chunk] = bl; }
}

// Pass 2: merge the NCHUNK chunk partials per batch, emit context and normalized weights.
__global__ __launch_bounds__(256) void attn_pass2(
    const float* __restrict__ po, const float* __restrict__ pm, const float* __restrict__ pl,
    float* __restrict__ ctx, float* __restrict__ wts)
{
  const int b = blockIdx.x;
  const int t = threadIdx.x;
  __shared__ float s_scale[NCHUNK];
  __shared__ float s_m, s_invl;
  if (t == 0) {
    float m = -3.0e38f;
    for (int j = 0; j < NCHUNK; ++j) m = fmaxf(m, pm[b * NCHUNK + j]);
    float l = 0.0f;
    for (int j = 0; j < NCHUNK; ++j) {
      const float sc = __expf(pm[b * NCHUNK + j] - m);
      s_scale[j] = sc;
      l += pl[b * NCHUNK + j] * sc;
    }
    s_m = m; s_invl = 1.0f / l;
  }
  __syncthreads();
  const float m = s_m, invl = s_invl;

  vfloat4 acc = {0,0,0,0};
  for (int j = 0; j < NCHUNK; ++j) {
    const vfloat4 ow = ((const vfloat4*)po)[((size_t)b * NCHUNK + j) * H4 + t];
    acc += ow * s_scale[j];
  }
  acc *= invl;
  ((vfloat4*)ctx)[(size_t)b * H4 + t] = acc;

  // Normalize stored raw scores in place.
  for (int s = t; s < S; s += 256) {
    const float sc = wts[(size_t)b * S + s];
    wts[(size_t)b * S + s] = __expf(sc - m) * invl;
  }
}

extern "C" void kernel_launch(void* const* d_in, const int* in_sizes, int n_in,
                              void* d_out, int out_size, void* d_ws, size_t ws_size,
                              hipStream_t stream) {
  const float* query = (const float*)d_in[0];   // 32*1*1024
  const float* keys  = (const float*)d_in[1];   // 32*4096*1024

  float* ctx = (float*)d_out;                   // context: first 32*1024 floats
  float* wts = (float*)d_out + BATCH * H;       // weights: next 32*4096 floats

  float* po = (float*)d_ws;                     // 32*32*1024 floats = 4 MiB
  float* pm = po + (size_t)BATCH * NCHUNK * H;  // 1024 floats
  float* pl = pm + BATCH * NCHUNK;              // 1024 floats

  attn_pass1<<<dim3(NCHUNK, BATCH), BLOCK, 0, stream>>>(query, keys, wts, po, pm, pl);
  attn_pass2<<<BATCH, 256, 0, stream>>>(po, pm, pl, ctx, wts);
}